// Round 3
// baseline (3230.431 us; speedup 1.0000x reference)
//
#include <hip/hip_runtime.h>
#include <math.h>

#define BB 48
#define TT 32
#define DD 1024
#define SZ 512
#define NCELLS 528  // 32*33/2
#define BKT 16      // transform k-step

__device__ __forceinline__ int off_of(int k) { return TT * k - (k * (k - 1)) / 2; }

// ---------------------------------------------------------------------------
// Leaf GEMM: chart_h[:, :32] = relu(x @ w_leaf + b_leaf)  (pre-normalization)
// ---------------------------------------------------------------------------
__global__ __launch_bounds__(256) void leaf_gemm(
    const float* __restrict__ x, const float* __restrict__ w_leaf,
    const float* __restrict__ b_leaf, float* __restrict__ chart_h)
{
    __shared__ float Xs[32][36];
    __shared__ float Bs[32][64];
    const int t = threadIdx.x;
    const int col0 = blockIdx.x * 64;
    const int row0 = blockIdx.y * 32;

    const int ar = t >> 3;
    const int ak = (t & 7) * 4;
    const float* aptr = x + (size_t)(row0 + ar) * DD + ak;

    const int bslot = t & 15;
    const int brow = t >> 4;
    const float* bptr = w_leaf + (size_t)brow * SZ + col0 + bslot * 4;

    const int ty = t >> 4, tx = t & 15;
    float acc[2][4];
    #pragma unroll
    for (int i = 0; i < 2; ++i)
        #pragma unroll
        for (int j = 0; j < 4; ++j) acc[i][j] = 0.f;

    for (int k0 = 0; k0 < DD; k0 += 32) {
        __syncthreads();
        {
            float4 v = *(const float4*)(aptr + k0);
            Xs[ak + 0][ar] = v.x; Xs[ak + 1][ar] = v.y;
            Xs[ak + 2][ar] = v.z; Xs[ak + 3][ar] = v.w;
        }
        #pragma unroll
        for (int p = 0; p < 2; ++p) {
            *(float4*)&Bs[brow + p * 16][bslot * 4] =
                *(const float4*)(bptr + (size_t)(k0 + p * 16) * SZ);
        }
        __syncthreads();
        #pragma unroll
        for (int k = 0; k < 32; ++k) {
            float2 a2 = *(const float2*)&Xs[k][ty * 2];
            float4 b4 = *(const float4*)&Bs[k][tx * 4];
            float av[2] = {a2.x, a2.y};
            float bv[4] = {b4.x, b4.y, b4.z, b4.w};
            #pragma unroll
            for (int i = 0; i < 2; ++i)
                #pragma unroll
                for (int j = 0; j < 4; ++j)
                    acc[i][j] = fmaf(av[i], bv[j], acc[i][j]);
        }
    }

    float4 bc = *(const float4*)&b_leaf[col0 + tx * 4];
    #pragma unroll
    for (int i = 0; i < 2; ++i) {
        int g = row0 + ty * 2 + i;
        int b = g >> 5, pos = g & 31;
        float4 v;
        v.x = fmaxf(acc[i][0] + bc.x, 0.f);
        v.y = fmaxf(acc[i][1] + bc.y, 0.f);
        v.z = fmaxf(acc[i][2] + bc.z, 0.f);
        v.w = fmaxf(acc[i][3] + bc.w, 0.f);
        *(float4*)&chart_h[((size_t)b * NCELLS + pos) * SZ + col0 + tx * 4] = v;
    }
}

__global__ __launch_bounds__(256) void leaf_norm(
    float* __restrict__ chart_h, float* __restrict__ Sarr)
{
    const int r = blockIdx.x;
    const int b = r >> 5, pos = r & 31;
    const size_t base = ((size_t)b * NCELLS + pos) * SZ;
    const int t = threadIdx.x, lane = t & 63, wave = t >> 6;
    __shared__ float red[4];

    float2 v = *(const float2*)&chart_h[base + 2 * t];
    float sq = v.x * v.x + v.y * v.y;
    #pragma unroll
    for (int o = 32; o; o >>= 1) sq += __shfl_xor(sq, o);
    if (lane == 0) red[wave] = sq;
    __syncthreads();
    float nrm = sqrtf(red[0] + red[1] + red[2] + red[3]);
    float inv = 1.f / fmaxf(nrm, 1e-12f);
    v.x *= inv; v.y *= inv;
    *(float2*)&chart_h[base + 2 * t] = v;
    if (t == 0) Sarr[(size_t)b * NCELLS + pos] = 0.f;
}

// ---------------------------------------------------------------------------
// Transform v3: (B*L x 512) x (512 x 1536) fp32 GEMM.
// 1-wave (64-thread) blocks, 64x64 tile, 8x8 acc/lane, BK=16,
// register-prefetch pipeline, XCD-swizzled so each XCD owns 3 weight
// col-tiles (L2-resident). grid = 24 * nrow (always % 8 == 0).
// ---------------------------------------------------------------------------
__global__ __launch_bounds__(64) void transform_kernel(
    const float* __restrict__ chart_h, const float* __restrict__ w_comp,
    const float* __restrict__ s_bil,
    float* __restrict__ Ao, float* __restrict__ Co, float* __restrict__ Uo,
    int level, int nrow)
{
    __shared__ float As[BKT][72];   // k-major (transposed), pad 8
    __shared__ float Bs[BKT][64];

    const int L = TT - level;
    const int rows = BB * L;
    const int off = off_of(level);

    // XCD swizzle: hw block id -> work id; cpx = 3*nrow blocks per XCD,
    // so XCD x handles col-tiles [3x, 3x+3) for every row-tile.
    const int cpx = 3 * nrow;
    const int id = blockIdx.x;
    const int w = (id & 7) * cpx + (id >> 3);
    const int ct = w / nrow;        // 0..23
    const int rt = w % nrow;
    const int col0 = (ct & 7) * 64;

    const float* W; float* Out;
    const int sel = ct >> 3;
    if (sel == 0)      { W = w_comp;                   Out = Ao; }
    else if (sel == 1) { W = w_comp + (size_t)SZ * SZ; Out = Co; }
    else               { W = s_bil;                    Out = Uo; }

    const int t = threadIdx.x;

    // A staging: 4 passes, 16 rows each; lane -> (row = t>>2, kq = (t&3)*4)
    const int arow = t >> 2;
    const int akq = (t & 3) * 4;
    const float* apt[4];
    #pragma unroll
    for (int p = 0; p < 4; ++p) {
        int g = rt * 64 + p * 16 + arow;
        if (g < rows) {
            int b = g / L, pos = g % L;
            apt[p] = chart_h + ((size_t)b * NCELLS + off + pos) * SZ + akq;
        } else apt[p] = nullptr;
    }
    // B staging: 4 passes, 4 k-rows each; lane -> (k = t>>4, col = (t&15)*4)
    const int bk = t >> 4;
    const int bco = (t & 15) * 4;
    const float* bptr = W + (size_t)bk * SZ + col0 + bco;

    const int ro = (t >> 3) * 8;    // output rows ro..ro+7
    const int co = (t & 7) * 8;     // output cols co..co+7

    float acc[8][8];
    #pragma unroll
    for (int i = 0; i < 8; ++i)
        #pragma unroll
        for (int j = 0; j < 8; ++j) acc[i][j] = 0.f;

    float4 pa[4], pb[4];
    #pragma unroll
    for (int p = 0; p < 4; ++p) {
        pa[p] = apt[p] ? *(const float4*)(apt[p]) : make_float4(0.f, 0.f, 0.f, 0.f);
        pb[p] = *(const float4*)(bptr + (size_t)(p * 4) * SZ);
    }

    for (int k0 = 0; k0 < SZ; k0 += BKT) {
        __syncthreads();
        #pragma unroll
        for (int p = 0; p < 4; ++p) {
            As[akq + 0][p * 16 + arow] = pa[p].x;
            As[akq + 1][p * 16 + arow] = pa[p].y;
            As[akq + 2][p * 16 + arow] = pa[p].z;
            As[akq + 3][p * 16 + arow] = pa[p].w;
            *(float4*)&Bs[bk + p * 4][bco] = pb[p];
        }
        __syncthreads();

        if (k0 + BKT < SZ) {
            #pragma unroll
            for (int p = 0; p < 4; ++p) {
                pa[p] = apt[p] ? *(const float4*)(apt[p] + k0 + BKT)
                               : make_float4(0.f, 0.f, 0.f, 0.f);
                pb[p] = *(const float4*)(bptr + (size_t)(k0 + BKT + p * 4) * SZ);
            }
        }

        #pragma unroll
        for (int k = 0; k < BKT; ++k) {
            float4 a0 = *(const float4*)&As[k][ro];
            float4 a1 = *(const float4*)&As[k][ro + 4];
            float4 b0 = *(const float4*)&Bs[k][co];
            float4 b1 = *(const float4*)&Bs[k][co + 4];
            float av[8] = {a0.x, a0.y, a0.z, a0.w, a1.x, a1.y, a1.z, a1.w};
            float bv[8] = {b0.x, b0.y, b0.z, b0.w, b1.x, b1.y, b1.z, b1.w};
            #pragma unroll
            for (int i = 0; i < 8; ++i)
                #pragma unroll
                for (int j = 0; j < 8; ++j)
                    acc[i][j] = fmaf(av[i], bv[j], acc[i][j]);
        }
    }

    #pragma unroll
    for (int i = 0; i < 8; ++i) {
        int g = rt * 64 + ro + i;
        if (g < rows) {
            int b = g / L, pos = g % L;
            size_t base = ((size_t)b * NCELLS + off + pos) * SZ + col0 + co;
            *(float4*)&Out[base] =
                make_float4(acc[i][0], acc[i][1], acc[i][2], acc[i][3]);
            *(float4*)&Out[base + 4] =
                make_float4(acc[i][4], acc[i][5], acc[i][6], acc[i][7]);
        }
    }
}

// ---------------------------------------------------------------------------
// Combine: one block per (b, pos) at `level`.
// ---------------------------------------------------------------------------
__global__ __launch_bounds__(256) void combine_kernel(
    float* __restrict__ chart_h,
    const float* __restrict__ Aarr, const float* __restrict__ Carr,
    const float* __restrict__ Uarr, float* __restrict__ Sarr,
    const float* __restrict__ b_comp, int level)
{
    const int L = TT - level, N = level;
    const int bid = blockIdx.x;
    const int b = bid / L, pos = bid % L;
    const int off = off_of(level);

    __shared__ float s_lds[32], p_lds[32];
    __shared__ int lcell[32], rcell[32];
    __shared__ float red[4];

    const int t = threadIdx.x, lane = t & 63, wave = t >> 6;

    if (t < N) {
        lcell[t] = off_of(t) + pos;
        rcell[t] = off_of(level - t - 1) + pos + t + 1;
    }
    __syncthreads();

    for (int n = wave; n < N; n += 4) {
        const float* u  = Uarr    + ((size_t)b * NCELLS + lcell[n]) * SZ;
        const float* hr = chart_h + ((size_t)b * NCELLS + rcell[n]) * SZ;
        float d = 0.f;
        #pragma unroll
        for (int jj = 0; jj < 4; ++jj) {
            int j = lane * 2 + jj * 128;
            float2 uv = *(const float2*)&u[j];
            float2 hv = *(const float2*)&hr[j];
            d = fmaf(uv.x, hv.x, d);
            d = fmaf(uv.y, hv.y, d);
        }
        #pragma unroll
        for (int o = 32; o; o >>= 1) d += __shfl_xor(d, o);
        if (lane == 0)
            s_lds[n] = d + Sarr[(size_t)b * NCELLS + lcell[n]]
                         + Sarr[(size_t)b * NCELLS + rcell[n]];
    }
    __syncthreads();

    if (wave == 0) {
        float sv = (lane < N) ? s_lds[lane] : -INFINITY;
        float m = sv;
        #pragma unroll
        for (int o = 32; o; o >>= 1) m = fmaxf(m, __shfl_xor(m, o));
        float e = (lane < N) ? expf(sv - m) : 0.f;
        float sum = e;
        #pragma unroll
        for (int o = 32; o; o >>= 1) sum += __shfl_xor(sum, o);
        float p = e / sum;
        if (lane < N) p_lds[lane] = p;
        float sb = (lane < N) ? sv * p : 0.f;
        #pragma unroll
        for (int o = 32; o; o >>= 1) sb += __shfl_xor(sb, o);
        if (lane == 0) Sarr[(size_t)b * NCELLS + off + pos] = sb;
    }
    __syncthreads();

    const int j = 2 * t;
    float2 bc = *(const float2*)&b_comp[j];
    float hx = 0.f, hy = 0.f;
    for (int n = 0; n < N; ++n) {
        size_t lbase = ((size_t)b * NCELLS + lcell[n]) * SZ;
        size_t rbase = ((size_t)b * NCELLS + rcell[n]) * SZ;
        float p = p_lds[n];
        float2 va = *(const float2*)&Aarr[lbase + j];
        float2 vc = *(const float2*)&Carr[rbase + j];
        hx = fmaf(p, fmaxf(va.x + vc.x + bc.x, 0.f), hx);
        hy = fmaf(p, fmaxf(va.y + vc.y + bc.y, 0.f), hy);
    }

    float sq = hx * hx + hy * hy;
    #pragma unroll
    for (int o = 32; o; o >>= 1) sq += __shfl_xor(sq, o);
    if (lane == 0) red[wave] = sq;
    __syncthreads();
    float nrm = sqrtf(red[0] + red[1] + red[2] + red[3]);
    float inv = 1.f / fmaxf(nrm, 1e-12f);
    size_t obase = ((size_t)b * NCELLS + off + pos) * SZ;
    *(float2*)&chart_h[obase + j] = make_float2(hx * inv, hy * inv);
}

// ---------------------------------------------------------------------------
extern "C" void kernel_launch(void* const* d_in, const int* in_sizes, int n_in,
                              void* d_out, int out_size, void* d_ws, size_t ws_size,
                              hipStream_t stream)
{
    const float* x      = (const float*)d_in[0];
    const float* w_leaf = (const float*)d_in[1];
    const float* b_leaf = (const float*)d_in[2];
    const float* w_comp = (const float*)d_in[3];
    const float* b_comp = (const float*)d_in[4];
    const float* s_bil  = (const float*)d_in[5];
    float* chart_h = (float*)d_out;

    float* ws   = (float*)d_ws;
    const size_t cellsz = (size_t)BB * NCELLS * SZ;
    float* Aarr = ws;
    float* Carr = Aarr + cellsz;
    float* Uarr = Carr + cellsz;
    float* Sarr = Uarr + cellsz;

    leaf_gemm<<<dim3(8, 48), 256, 0, stream>>>(x, w_leaf, b_leaf, chart_h);
    leaf_norm<<<BB * TT, 256, 0, stream>>>(chart_h, Sarr);

    {
        int nrow = (BB * TT + 63) / 64;   // 24
        transform_kernel<<<24 * nrow, 64, 0, stream>>>(
            chart_h, w_comp, s_bil, Aarr, Carr, Uarr, 0, nrow);
    }

    for (int level = 1; level < TT; ++level) {
        int L = TT - level;
        combine_kernel<<<BB * L, 256, 0, stream>>>(
            chart_h, Aarr, Carr, Uarr, Sarr, b_comp, level);
        if (level < TT - 1) {
            int nrow = (BB * L + 63) / 64;
            transform_kernel<<<24 * nrow, 64, 0, stream>>>(
                chart_h, w_comp, s_bil, Aarr, Carr, Uarr, level, nrow);
        }
    }
}

// Round 4
// 1102.872 us; speedup vs baseline: 2.9291x; 2.9291x over previous
//
#include <hip/hip_runtime.h>
#include <math.h>

#define BB 48
#define TT 32
#define DD 1024
#define SZ 512
#define NCELLS 528  // 32*33/2

typedef unsigned short u16;
typedef unsigned int u32;
typedef __attribute__((ext_vector_type(8))) short bf16x8;
typedef __attribute__((ext_vector_type(4))) float f32x4;

__device__ __forceinline__ int off_of(int k) { return TT * k - (k * (k - 1)) / 2; }

__device__ __forceinline__ u16 f2bf(float x) {
    u32 u = __float_as_uint(x);
    u32 r = (u + 0x7fffu + ((u >> 16) & 1u)) >> 16;
    return (u16)r;
}
__device__ __forceinline__ float bf2f(u16 h) {
    return __uint_as_float(((u32)h) << 16);
}
__device__ __forceinline__ u32 pack2(u16 a, u16 b) {
    return (u32)a | ((u32)b << 16);
}

// ---------------------------------------------------------------------------
// prep_w: split + transpose weights.
// Wcat[k][n] (512 x 1536) = [Wtop | Wbot | S]; WT[n][k] col-major, bf16 hi/lo.
// ---------------------------------------------------------------------------
__global__ __launch_bounds__(256) void prep_w(
    const float* __restrict__ w_comp, const float* __restrict__ s_bil,
    u16* __restrict__ WT_hi, u16* __restrict__ WT_lo)
{
    int idx = blockIdx.x * 256 + threadIdx.x;   // n*512 + k
    int n = idx >> 9, k = idx & 511;
    float w;
    if (n < 512)       w = w_comp[(size_t)k * SZ + n];
    else if (n < 1024) w = w_comp[(size_t)(512 + k) * SZ + (n - 512)];
    else               w = s_bil[(size_t)k * SZ + (n - 1024)];
    u16 hi = f2bf(w);
    u16 lo = f2bf(w - bf2f(hi));
    WT_hi[idx] = hi;
    WT_lo[idx] = lo;
}

// ---------------------------------------------------------------------------
// Leaf GEMM: chart_h[:, :32] = relu(x @ w_leaf + b_leaf) (pre-norm)
// ---------------------------------------------------------------------------
__global__ __launch_bounds__(256) void leaf_gemm(
    const float* __restrict__ x, const float* __restrict__ w_leaf,
    const float* __restrict__ b_leaf, float* __restrict__ chart_h)
{
    __shared__ float Xs[32][36];
    __shared__ float Bs[32][64];
    const int t = threadIdx.x;
    const int col0 = blockIdx.x * 64;
    const int row0 = blockIdx.y * 32;

    const int ar = t >> 3;
    const int ak = (t & 7) * 4;
    const float* aptr = x + (size_t)(row0 + ar) * DD + ak;

    const int bslot = t & 15;
    const int brow = t >> 4;
    const float* bptr = w_leaf + (size_t)brow * SZ + col0 + bslot * 4;

    const int ty = t >> 4, tx = t & 15;
    float acc[2][4];
    #pragma unroll
    for (int i = 0; i < 2; ++i)
        #pragma unroll
        for (int j = 0; j < 4; ++j) acc[i][j] = 0.f;

    for (int k0 = 0; k0 < DD; k0 += 32) {
        __syncthreads();
        {
            float4 v = *(const float4*)(aptr + k0);
            Xs[ak + 0][ar] = v.x; Xs[ak + 1][ar] = v.y;
            Xs[ak + 2][ar] = v.z; Xs[ak + 3][ar] = v.w;
        }
        #pragma unroll
        for (int p = 0; p < 2; ++p) {
            *(float4*)&Bs[brow + p * 16][bslot * 4] =
                *(const float4*)(bptr + (size_t)(k0 + p * 16) * SZ);
        }
        __syncthreads();
        #pragma unroll
        for (int k = 0; k < 32; ++k) {
            float2 a2 = *(const float2*)&Xs[k][ty * 2];
            float4 b4 = *(const float4*)&Bs[k][tx * 4];
            float av[2] = {a2.x, a2.y};
            float bv[4] = {b4.x, b4.y, b4.z, b4.w};
            #pragma unroll
            for (int i = 0; i < 2; ++i)
                #pragma unroll
                for (int j = 0; j < 4; ++j)
                    acc[i][j] = fmaf(av[i], bv[j], acc[i][j]);
        }
    }

    float4 bc = *(const float4*)&b_leaf[col0 + tx * 4];
    #pragma unroll
    for (int i = 0; i < 2; ++i) {
        int g = row0 + ty * 2 + i;
        int b = g >> 5, pos = g & 31;
        float4 v;
        v.x = fmaxf(acc[i][0] + bc.x, 0.f);
        v.y = fmaxf(acc[i][1] + bc.y, 0.f);
        v.z = fmaxf(acc[i][2] + bc.z, 0.f);
        v.w = fmaxf(acc[i][3] + bc.w, 0.f);
        *(float4*)&chart_h[((size_t)b * NCELLS + pos) * SZ + col0 + tx * 4] = v;
    }
}

__global__ __launch_bounds__(256) void leaf_norm(
    float* __restrict__ chart_h, float* __restrict__ Sarr)
{
    const int r = blockIdx.x;
    const int b = r >> 5, pos = r & 31;
    const size_t base = ((size_t)b * NCELLS + pos) * SZ;
    const int t = threadIdx.x, lane = t & 63, wave = t >> 6;
    __shared__ float red[4];

    float2 v = *(const float2*)&chart_h[base + 2 * t];
    float sq = v.x * v.x + v.y * v.y;
    #pragma unroll
    for (int o = 32; o; o >>= 1) sq += __shfl_xor(sq, o);
    if (lane == 0) red[wave] = sq;
    __syncthreads();
    float nrm = sqrtf(red[0] + red[1] + red[2] + red[3]);
    float inv = 1.f / fmaxf(nrm, 1e-12f);
    v.x *= inv; v.y *= inv;
    *(float2*)&chart_h[base + 2 * t] = v;
    if (t == 0) Sarr[(size_t)b * NCELLS + pos] = 0.f;
}

// ---------------------------------------------------------------------------
// transform_mfma: ACU[cell][0:1536] = h[cell] @ Wcat, split-bf16 (3 MFMA
// products -> fp32-accurate). Block tile 128 rows x 64 cols, 4 waves (2x2),
// wave tile 64x32, mfma_f32_16x16x32_bf16, BK=32, reg-prefetch pipeline.
// ---------------------------------------------------------------------------
__global__ __launch_bounds__(256) void transform_mfma(
    const float* __restrict__ chart_h,
    const u16* __restrict__ WT_hi, const u16* __restrict__ WT_lo,
    float* __restrict__ ACU, int level, int nrow)
{
    __shared__ u16 Ah[128][40], Al[128][40];   // 10240 B each
    __shared__ u16 Bh[64][40],  Bl[64][40];    // 5120 B each
    __shared__ int cidx[128];

    const int L = TT - level, rows = BB * L, off = off_of(level);
    const int id = blockIdx.x;
    const int rt = id % nrow, ct = id / nrow;   // ct 0..23
    const int col0 = ct * 64;

    const int t = threadIdx.x;
    if (t < 128) {
        int g = rt * 128 + t;
        cidx[t] = (g < rows) ? ((g / L) * NCELLS + off + (g % L)) : -1;
    }
    __syncthreads();

    // A staging: thread -> (row = t>>1, k-half = (t&1)*16), 16 f32 per step
    const int srow = t >> 1, skh = (t & 1) * 16;
    const float* ap = (cidx[srow] >= 0)
        ? chart_h + (size_t)cidx[srow] * SZ + skh : nullptr;
    // B staging: thread -> (col = t>>2, chunk = (t&3)*8), 8 u16 x2 per step
    const int bcol = t >> 2, bch = (t & 3) * 8;
    const u16* bph = WT_hi + (size_t)(col0 + bcol) * SZ + bch;
    const u16* bpl = WT_lo + (size_t)(col0 + bcol) * SZ + bch;

    // wave tiling: 2x2 waves; wave tile 64 rows x 32 cols
    const int lane = t & 63, wv = t >> 6;
    const int wr = wv >> 1, wc = wv & 1;
    const int l15 = lane & 15, lko = (lane >> 4) * 8;

    f32x4 acc[4][2];
    #pragma unroll
    for (int i = 0; i < 4; ++i)
        #pragma unroll
        for (int j = 0; j < 2; ++j)
            #pragma unroll
            for (int e = 0; e < 4; ++e) acc[i][j][e] = 0.f;

    float4 pa[4];
    uint4 pbh, pbl;
    #pragma unroll
    for (int c = 0; c < 4; ++c)
        pa[c] = ap ? *(const float4*)(ap + c * 4)
                   : make_float4(0.f, 0.f, 0.f, 0.f);
    pbh = *(const uint4*)bph;
    pbl = *(const uint4*)bpl;

    for (int k0 = 0; k0 < SZ; k0 += 32) {
        // write staged regs -> LDS (split A to hi/lo on the fly)
        u32 wh[8], wl[8];
        #pragma unroll
        for (int c = 0; c < 4; ++c) {
            float xs[4] = {pa[c].x, pa[c].y, pa[c].z, pa[c].w};
            u16 hh[4], ll[4];
            #pragma unroll
            for (int e = 0; e < 4; ++e) {
                hh[e] = f2bf(xs[e]);
                ll[e] = f2bf(xs[e] - bf2f(hh[e]));
            }
            wh[c * 2]     = pack2(hh[0], hh[1]);
            wh[c * 2 + 1] = pack2(hh[2], hh[3]);
            wl[c * 2]     = pack2(ll[0], ll[1]);
            wl[c * 2 + 1] = pack2(ll[2], ll[3]);
        }
        *(uint4*)&Ah[srow][skh]     = make_uint4(wh[0], wh[1], wh[2], wh[3]);
        *(uint4*)&Ah[srow][skh + 8] = make_uint4(wh[4], wh[5], wh[6], wh[7]);
        *(uint4*)&Al[srow][skh]     = make_uint4(wl[0], wl[1], wl[2], wl[3]);
        *(uint4*)&Al[srow][skh + 8] = make_uint4(wl[4], wl[5], wl[6], wl[7]);
        *(uint4*)&Bh[bcol][bch] = pbh;
        *(uint4*)&Bl[bcol][bch] = pbl;
        __syncthreads();

        // prefetch next k-step
        if (k0 + 32 < SZ) {
            #pragma unroll
            for (int c = 0; c < 4; ++c)
                pa[c] = ap ? *(const float4*)(ap + k0 + 32 + c * 4)
                           : make_float4(0.f, 0.f, 0.f, 0.f);
            pbh = *(const uint4*)(bph + k0 + 32);
            pbl = *(const uint4*)(bpl + k0 + 32);
        }

        // fragments + MFMA
        bf16x8 fah[4], fal[4], fbh[2], fbl[2];
        #pragma unroll
        for (int i = 0; i < 4; ++i) {
            fah[i] = *(const bf16x8*)&Ah[wr * 64 + i * 16 + l15][lko];
            fal[i] = *(const bf16x8*)&Al[wr * 64 + i * 16 + l15][lko];
        }
        #pragma unroll
        for (int j = 0; j < 2; ++j) {
            fbh[j] = *(const bf16x8*)&Bh[wc * 32 + j * 16 + l15][lko];
            fbl[j] = *(const bf16x8*)&Bl[wc * 32 + j * 16 + l15][lko];
        }
        #pragma unroll
        for (int i = 0; i < 4; ++i) {
            #pragma unroll
            for (int j = 0; j < 2; ++j) {
                acc[i][j] = __builtin_amdgcn_mfma_f32_16x16x32_bf16(
                    fah[i], fbh[j], acc[i][j], 0, 0, 0);
                acc[i][j] = __builtin_amdgcn_mfma_f32_16x16x32_bf16(
                    fah[i], fbl[j], acc[i][j], 0, 0, 0);
                acc[i][j] = __builtin_amdgcn_mfma_f32_16x16x32_bf16(
                    fal[i], fbh[j], acc[i][j], 0, 0, 0);
            }
        }
        __syncthreads();
    }

    // epilogue: C/D layout col = lane&15, row = (lane>>4)*4 + reg
    #pragma unroll
    for (int i = 0; i < 4; ++i) {
        int rbase = wr * 64 + i * 16 + (lane >> 4) * 4;
        #pragma unroll
        for (int j = 0; j < 2; ++j) {
            int gc = col0 + wc * 32 + j * 16 + l15;
            #pragma unroll
            for (int q = 0; q < 4; ++q) {
                int ci = cidx[rbase + q];
                if (ci >= 0)
                    ACU[(size_t)ci * 1536 + gc] = acc[i][j][q];
            }
        }
    }
}

// ---------------------------------------------------------------------------
// Combine: one block per (b, pos). Phase 2 parallelized over n across waves.
// ---------------------------------------------------------------------------
__global__ __launch_bounds__(256) void combine_kernel(
    float* __restrict__ chart_h, const float* __restrict__ ACU,
    float* __restrict__ Sarr, const float* __restrict__ b_comp, int level)
{
    const int L = TT - level, N = level;
    const int b = blockIdx.x / L, pos = blockIdx.x % L;
    const int off = off_of(level);

    __shared__ float s_lds[32], p_lds[32];
    __shared__ int lcell[32], rcell[32];
    __shared__ float hred[4][512];
    __shared__ float red[4];

    const int t = threadIdx.x, lane = t & 63, wv = t >> 6;

    if (t < N) {
        lcell[t] = b * NCELLS + off_of(t) + pos;
        rcell[t] = b * NCELLS + off_of(level - t - 1) + pos + t + 1;
    }
    __syncthreads();

    // phase 1: s_n = (h_l @ S) . h_r + s_l + s_r
    for (int n = wv; n < N; n += 4) {
        const float* u  = ACU + (size_t)lcell[n] * 1536 + 1024;
        const float* hr = chart_h + (size_t)rcell[n] * SZ;
        float d0 = 0.f, d1 = 0.f, d2 = 0.f, d3 = 0.f;
        int j = lane * 2;
        {
            float2 uv = *(const float2*)&u[j];
            float2 hv = *(const float2*)&hr[j];
            d0 = fmaf(uv.x, hv.x, fmaf(uv.y, hv.y, d0));
        }
        {
            float2 uv = *(const float2*)&u[j + 128];
            float2 hv = *(const float2*)&hr[j + 128];
            d1 = fmaf(uv.x, hv.x, fmaf(uv.y, hv.y, d1));
        }
        {
            float2 uv = *(const float2*)&u[j + 256];
            float2 hv = *(const float2*)&hr[j + 256];
            d2 = fmaf(uv.x, hv.x, fmaf(uv.y, hv.y, d2));
        }
        {
            float2 uv = *(const float2*)&u[j + 384];
            float2 hv = *(const float2*)&hr[j + 384];
            d3 = fmaf(uv.x, hv.x, fmaf(uv.y, hv.y, d3));
        }
        float d = (d0 + d1) + (d2 + d3);
        #pragma unroll
        for (int o = 32; o; o >>= 1) d += __shfl_xor(d, o);
        if (lane == 0)
            s_lds[n] = d + Sarr[lcell[n]] + Sarr[rcell[n]];
    }
    __syncthreads();

    // phase 1b: softmax over N (wave 0) + sbar
    if (wv == 0) {
        float sv = (lane < N) ? s_lds[lane] : -INFINITY;
        float m = sv;
        #pragma unroll
        for (int o = 32; o; o >>= 1) m = fmaxf(m, __shfl_xor(m, o));
        float e = (lane < N) ? expf(sv - m) : 0.f;
        float sum = e;
        #pragma unroll
        for (int o = 32; o; o >>= 1) sum += __shfl_xor(sum, o);
        float p = e / sum;
        if (lane < N) p_lds[lane] = p;
        float sb = (lane < N) ? sv * p : 0.f;
        #pragma unroll
        for (int o = 32; o; o >>= 1) sb += __shfl_xor(sb, o);
        if (lane == 0) Sarr[(size_t)b * NCELLS + off + pos] = sb;
    }
    __syncthreads();

    // phase 2: per-wave partial hbar over n subset, 4 float2 lanes each
    float ax[4], ay[4];
    float2 bc[4];
    #pragma unroll
    for (int q = 0; q < 4; ++q) {
        ax[q] = 0.f; ay[q] = 0.f;
        bc[q] = *(const float2*)&b_comp[lane * 2 + q * 128];
    }
    for (int n = wv; n < N; n += 4) {
        const float* A_ = ACU + (size_t)lcell[n] * 1536;
        const float* C_ = ACU + (size_t)rcell[n] * 1536 + 512;
        float p = p_lds[n];
        #pragma unroll
        for (int q = 0; q < 4; ++q) {
            int j = lane * 2 + q * 128;
            float2 va = *(const float2*)&A_[j];
            float2 vc = *(const float2*)&C_[j];
            ax[q] = fmaf(p, fmaxf(va.x + vc.x + bc[q].x, 0.f), ax[q]);
            ay[q] = fmaf(p, fmaxf(va.y + vc.y + bc[q].y, 0.f), ay[q]);
        }
    }
    #pragma unroll
    for (int q = 0; q < 4; ++q)
        *(float2*)&hred[wv][lane * 2 + q * 128] = make_float2(ax[q], ay[q]);
    __syncthreads();

    float hx = hred[0][2 * t] + hred[1][2 * t] + hred[2][2 * t] + hred[3][2 * t];
    float hy = hred[0][2 * t + 1] + hred[1][2 * t + 1]
             + hred[2][2 * t + 1] + hred[3][2 * t + 1];

    float sq = hx * hx + hy * hy;
    #pragma unroll
    for (int o = 32; o; o >>= 1) sq += __shfl_xor(sq, o);
    if (lane == 0) red[wv] = sq;
    __syncthreads();
    float nrm = sqrtf(red[0] + red[1] + red[2] + red[3]);
    float inv = 1.f / fmaxf(nrm, 1e-12f);
    size_t obase = ((size_t)b * NCELLS + off + pos) * SZ;
    *(float2*)&chart_h[obase + 2 * t] = make_float2(hx * inv, hy * inv);
}

// ---------------------------------------------------------------------------
extern "C" void kernel_launch(void* const* d_in, const int* in_sizes, int n_in,
                              void* d_out, int out_size, void* d_ws, size_t ws_size,
                              hipStream_t stream)
{
    const float* x      = (const float*)d_in[0];
    const float* w_leaf = (const float*)d_in[1];
    const float* b_leaf = (const float*)d_in[2];
    const float* w_comp = (const float*)d_in[3];
    const float* b_comp = (const float*)d_in[4];
    const float* s_bil  = (const float*)d_in[5];
    float* chart_h = (float*)d_out;

    // ws: ACU (48*528*1536 f32 = 155.7MB) + Sarr + WT_hi/lo (1.5MB each)
    float* ws = (float*)d_ws;
    float* ACU  = ws;
    float* Sarr = ACU + (size_t)BB * NCELLS * 1536;
    u16* WT_hi = (u16*)(Sarr + BB * NCELLS);
    u16* WT_lo = WT_hi + (size_t)1536 * SZ;

    prep_w<<<(1536 * SZ) / 256, 256, 0, stream>>>(w_comp, s_bil, WT_hi, WT_lo);
    leaf_gemm<<<dim3(8, 48), 256, 0, stream>>>(x, w_leaf, b_leaf, chart_h);
    leaf_norm<<<BB * TT, 256, 0, stream>>>(chart_h, Sarr);

    {
        int nrow = (BB * TT + 127) / 128;   // 12
        transform_mfma<<<24 * nrow, 256, 0, stream>>>(
            chart_h, WT_hi, WT_lo, ACU, 0, nrow);
    }

    for (int level = 1; level < TT; ++level) {
        int L = TT - level;
        combine_kernel<<<BB * L, 256, 0, stream>>>(
            chart_h, ACU, Sarr, b_comp, level);
        if (level < TT - 1) {
            int nrow = (BB * L + 127) / 128;
            transform_mfma<<<24 * nrow, 256, 0, stream>>>(
                chart_h, WT_hi, WT_lo, ACU, level, nrow);
        }
    }
}